// Round 1
// baseline (7940.997 us; speedup 1.0000x reference)
//
#include <hip/hip_runtime.h>
#include <math.h>

#define NB 32
#define NS 400
#define NM 400
#define NH 200
#define NP 16
#define NT 4
#define NBS (NB*NS)          // 12800
#define NPH (NP*NH)          // 3200
#define NX  (2*NM)           // 800  (LSTM input)
#define NG  (4*NH)           // 800  (LSTM gates)
#define NR  (2*NM+NH)        // 1000 (r input)

__device__ __forceinline__ float sigf(float x){ return 1.0f/(1.0f+expf(-x)); }

// ---------------- init: h=c=0, sprev=0, eprev=sum(mask)-1 ----------------
__global__ __launch_bounds__(256) void init_kernel(const float* __restrict__ mask,
    float* __restrict__ h, float* __restrict__ c,
    int* __restrict__ sprev, int* __restrict__ eprev){
  int b = blockIdx.x, tid = threadIdx.x;
  __shared__ float red[256];
  float s = 0.f;
  for (int i=tid;i<NS;i+=256) s += mask[(size_t)b*NS+i];
  red[tid]=s; __syncthreads();
  for (int st=128;st>0;st>>=1){ if(tid<st) red[tid]+=red[tid+st]; __syncthreads(); }
  if (tid==0){ sprev[b]=0; eprev[b]=(int)red[0]-1; }
  for (int i=tid;i<NH;i+=256){ h[(size_t)b*NH+i]=0.f; c[(size_t)b*NH+i]=0.f; }
}

// ---------------- LSTM cell: one block per batch row ----------------
__global__ __launch_bounds__(256) void lstm_kernel(const float* __restrict__ mod,
    const int* __restrict__ sprev, const int* __restrict__ eprev,
    const float* __restrict__ Wih, const float* __restrict__ Whh,
    const float* __restrict__ bih, const float* __restrict__ bhh,
    float* __restrict__ h, float* __restrict__ c){
  int b=blockIdx.x, tid=threadIdx.x;
  __shared__ float xs[NX];
  __shared__ float hs[NH];
  __shared__ float gs[NG];
  const float* us = mod + ((size_t)b*NS + sprev[b])*NM;
  const float* ue = mod + ((size_t)b*NS + eprev[b])*NM;
  for (int i=tid;i<NM;i+=256){ xs[i]=us[i]; xs[NM+i]=ue[i]; }
  for (int i=tid;i<NH;i+=256) hs[i]=h[(size_t)b*NH+i];
  __syncthreads();
  for (int j=tid;j<NG;j+=256){
    float acc = bih[j]+bhh[j];
    const float4* wr=(const float4*)(Wih+(size_t)j*NX);
    #pragma unroll 4
    for (int k=0;k<NX/4;k++){ float4 w=wr[k];
      acc+=xs[4*k]*w.x+xs[4*k+1]*w.y+xs[4*k+2]*w.z+xs[4*k+3]*w.w; }
    const float4* wh=(const float4*)(Whh+(size_t)j*NH);
    #pragma unroll 4
    for (int k=0;k<NH/4;k++){ float4 w=wh[k];
      acc+=hs[4*k]*w.x+hs[4*k+1]*w.y+hs[4*k+2]*w.z+hs[4*k+3]*w.w; }
    gs[j]=acc;
  }
  __syncthreads();
  for (int j=tid;j<NH;j+=256){
    float iv=gs[j], fv=gs[NH+j], gv=gs[2*NH+j], ov=gs[3*NH+j];
    float c2 = sigf(fv)*c[(size_t)b*NH+j] + sigf(iv)*tanhf(gv);
    c[(size_t)b*NH+j]=c2;
    h[(size_t)b*NH+j]=sigf(ov)*tanhf(c2);
  }
}

// ---- r = tanh([h,us,ue] @ rW^T); prer = r @ W1[:,400:]^T + b1 ; per-b block ----
__global__ __launch_bounds__(256) void r_prer_kernel(const float* __restrict__ mod,
    const int* __restrict__ sprev, const int* __restrict__ eprev,
    const float* __restrict__ h,
    const float* __restrict__ rW, const float* __restrict__ W1,
    const float* __restrict__ b1, float* __restrict__ prer){
  int b=blockIdx.x, tid=threadIdx.x;
  __shared__ float zs[NR];
  __shared__ float rsh[NH];
  for (int i=tid;i<NH;i+=256) zs[i]=h[(size_t)b*NH+i];
  const float* us = mod + ((size_t)b*NS + sprev[b])*NM;
  const float* ue = mod + ((size_t)b*NS + eprev[b])*NM;
  for (int i=tid;i<NM;i+=256){ zs[NH+i]=us[i]; zs[NH+NM+i]=ue[i]; }
  __syncthreads();
  for (int j=tid;j<NH;j+=256){
    float acc=0.f;
    const float4* wr=(const float4*)(rW+(size_t)j*NR);
    #pragma unroll 4
    for (int k=0;k<NR/4;k++){ float4 w=wr[k];
      acc+=zs[4*k]*w.x+zs[4*k+1]*w.y+zs[4*k+2]*w.z+zs[4*k+3]*w.w; }
    rsh[j]=tanhf(acc);
  }
  __syncthreads();
  for (int j=tid;j<NPH;j+=256){
    float acc=b1[j];
    const float4* w=(const float4*)(W1+(size_t)j*(NM+NH)+NM);
    #pragma unroll 4
    for (int k=0;k<NH/4;k++){ float4 ww=w[k];
      acc+=rsh[4*k]*ww.x+rsh[4*k+1]*ww.y+rsh[4*k+2]*ww.z+rsh[4*k+3]*ww.w; }
    prer[(size_t)b*NPH + j]=acc;
  }
}

// ---------------- generic f32 NT GEMM: C[i,j] = sum_k A[i,k]*W[j,k] ----------------
// tile 128x128, BK=8, 256 threads, 8x8 per-thread microtile. N (=3200) and rows
// multiples of 128, kdim multiple of 8, lda/ldw multiples of 4.
__global__ __launch_bounds__(256) void gemm_nt(const float* __restrict__ A, int lda,
    const float* __restrict__ W, int ldw, int kdim,
    float* __restrict__ C, int ldc){
  __shared__ __align__(16) float As[8][132];
  __shared__ __align__(16) float Ws[8][132];
  const int i0 = blockIdx.x*128, j0 = blockIdx.y*128;
  const int tid = threadIdx.x;
  const int lr = tid>>1, lk = (tid&1)*4;
  const float* Ap = A + (size_t)(i0+lr)*lda + lk;
  const float* Wp = W + (size_t)(j0+lr)*ldw + lk;
  const int ty = tid>>4, tx = tid&15;
  float acc[8][8];
  #pragma unroll
  for (int r=0;r<8;r++)
    #pragma unroll
    for (int cc=0;cc<8;cc++) acc[r][cc]=0.f;
  for (int kt=0; kt<kdim; kt+=8){
    float4 av = *(const float4*)(Ap + kt);
    float4 wv = *(const float4*)(Wp + kt);
    As[lk+0][lr]=av.x; As[lk+1][lr]=av.y; As[lk+2][lr]=av.z; As[lk+3][lr]=av.w;
    Ws[lk+0][lr]=wv.x; Ws[lk+1][lr]=wv.y; Ws[lk+2][lr]=wv.z; Ws[lk+3][lr]=wv.w;
    __syncthreads();
    #pragma unroll
    for (int k=0;k<8;k++){
      float4 a0 = *(const float4*)&As[k][ty*8];
      float4 a1 = *(const float4*)&As[k][ty*8+4];
      float4 b0 = *(const float4*)&Ws[k][tx*8];
      float4 b1 = *(const float4*)&Ws[k][tx*8+4];
      float a[8]={a0.x,a0.y,a0.z,a0.w,a1.x,a1.y,a1.z,a1.w};
      float bb[8]={b0.x,b0.y,b0.z,b0.w,b1.x,b1.y,b1.z,b1.w};
      #pragma unroll
      for (int r=0;r<8;r++)
        #pragma unroll
        for (int cc=0;cc<8;cc++) acc[r][cc] += a[r]*bb[cc];
    }
    __syncthreads();
  }
  #pragma unroll
  for (int r=0;r<8;r++){
    float* crow = C + (size_t)(i0+ty*8+r)*ldc + j0 + tx*8;
    *(float4*)crow     = make_float4(acc[r][0],acc[r][1],acc[r][2],acc[r][3]);
    *(float4*)(crow+4) = make_float4(acc[r][4],acc[r][5],acc[r][6],acc[r][7]);
  }
}

// --------- max over P: out[row,h] = max_p( pre[i, p*NH+h] + bias[(b)*NPH? + p*NH+h] ) ---------
__global__ __launch_bounds__(256) void maxp_kernel(const float* __restrict__ pre,
    const float* __restrict__ bias, int perB, int row0, float* __restrict__ out){
  int i = blockIdx.x;        // local row within this chunk / buffer
  int hh = threadIdx.x;
  if (hh >= NH) return;
  int absrow = row0 + i;
  const float* bs = bias + (perB ? (size_t)(absrow / NS) * NPH : 0);
  const float* pr = pre + (size_t)i * NPH;
  float v = -INFINITY;
  #pragma unroll
  for (int p=0;p<NP;p++) v = fmaxf(v, pr[p*NH+hh] + bs[p*NH+hh]);
  out[(size_t)absrow*NH + hh] = v;
}

// --------- logits (maxout-3) + mask + log_softmax + argmax; one block per b ---------
__global__ __launch_bounds__(256) void logits_kernel(const float* __restrict__ m1,
    const float* __restrict__ m2, const float* __restrict__ W3, const float* __restrict__ b3,
    const float* __restrict__ mask, float* __restrict__ out, int t, int* __restrict__ prevIdx){
  int b=blockIdx.x, tid=threadIdx.x;
  __shared__ float lg[NS];
  for (int s=tid; s<NS; s+=256){
    const float4* a = (const float4*)(m1 + ((size_t)b*NS+s)*NH);
    const float4* d = (const float4*)(m2 + ((size_t)b*NS+s)*NH);
    float acc[NP];
    #pragma unroll
    for (int p=0;p<NP;p++) acc[p]=b3[p];
    for (int k=0;k<NH/4;k++){
      float4 av=a[k], dv=d[k];
      #pragma unroll
      for (int p=0;p<NP;p++){
        const float* w = W3 + p*(2*NH) + 4*k;
        acc[p] += av.x*w[0]+av.y*w[1]+av.z*w[2]+av.w*w[3];
        const float* w2 = w + NH;
        acc[p] += dv.x*w2[0]+dv.y*w2[1]+dv.z*w2[2]+dv.w*w2[3];
      }
    }
    float best=acc[0];
    #pragma unroll
    for (int p=1;p<NP;p++) best=fmaxf(best,acc[p]);
    lg[s] = (mask[(size_t)b*NS+s] > 0.f) ? best : -1e30f;
  }
  __syncthreads();
  __shared__ float rv[256]; __shared__ int ri[256]; __shared__ float sv[256];
  float bv=-INFINITY; int bi=NS;
  for (int s=tid;s<NS;s+=256){ float v=lg[s]; if (v>bv){bv=v;bi=s;} }
  rv[tid]=bv; ri[tid]=bi; __syncthreads();
  for (int st=128;st>0;st>>=1){
    if (tid<st){
      float v2=rv[tid+st]; int i2=ri[tid+st];
      if (v2>rv[tid] || (v2==rv[tid] && i2<ri[tid])){ rv[tid]=v2; ri[tid]=i2; }
    }
    __syncthreads();
  }
  float mx = rv[0];
  float ps=0.f;
  for (int s=tid;s<NS;s+=256) ps += expf(lg[s]-mx);
  sv[tid]=ps; __syncthreads();
  for (int st=128;st>0;st>>=1){ if (tid<st) sv[tid]+=sv[tid+st]; __syncthreads(); }
  float lse = mx + logf(sv[0]);
  for (int s=tid;s<NS;s+=256) out[((size_t)b*NT + t)*NS + s] = lg[s]-lse;
  if (tid==0) prevIdx[b]=ri[0];
}

// =============================== host ===============================
extern "C" void kernel_launch(void* const* d_in, const int* in_sizes, int n_in,
                              void* d_out, int out_size, void* d_ws, size_t ws_size,
                              hipStream_t stream){
  const float* mod  = (const float*)d_in[1];
  const float* mask = (const float*)d_in[2];
  const float* Wih  = (const float*)d_in[3];
  const float* Whh  = (const float*)d_in[4];
  const float* bih  = (const float*)d_in[5];
  const float* bhh  = (const float*)d_in[6];
  const float* rW[2] = {(const float*)d_in[7],  (const float*)d_in[14]};
  const float* W1[2] = {(const float*)d_in[8],  (const float*)d_in[15]};
  const float* b1[2] = {(const float*)d_in[9],  (const float*)d_in[16]};
  const float* W2[2] = {(const float*)d_in[10], (const float*)d_in[17]};
  const float* b2[2] = {(const float*)d_in[11], (const float*)d_in[18]};
  const float* W3[2] = {(const float*)d_in[12], (const float*)d_in[19]};
  const float* b3[2] = {(const float*)d_in[13], (const float*)d_in[20]};
  float* out[2];
  out[0] = (float*)d_out;
  out[1] = out[0] + (size_t)NB*NT*NS;

  float* wsf = (float*)d_ws;
  size_t off = 0;
  auto carve = [&](size_t n)->size_t{ size_t o=off; off += (n + 63) & ~(size_t)63; return o; };
  size_t h_o    = carve((size_t)NB*NH);
  size_t c_o    = carve((size_t)NB*NH);
  size_t prer_o = carve((size_t)NB*NPH);
  size_t m1_o   = carve((size_t)NBS*NH);
  size_t m2_o   = carve((size_t)NBS*NH);
  size_t idx_o  = carve(128);
  float* hbuf = wsf + h_o;
  float* cbuf = wsf + c_o;
  float* prer = wsf + prer_o;
  float* m1   = wsf + m1_o;
  float* m2   = wsf + m2_o;
  int* sprev  = (int*)(wsf + idx_o);
  int* eprev  = sprev + 32;

  const size_t premodN = (size_t)NBS * NPH;       // 40.96M floats
  size_t availF = ws_size / 4;
  bool hoisted = availF >= off + 2*premodN + (size_t)128*NPH + 128;
  float* premod[2] = {nullptr, nullptr};
  if (hoisted){ premod[0] = wsf + carve(premodN); premod[1] = wsf + carve(premodN); }
  // premax chunk buffer gets the rest
  long chRows = 0;
  if (availF > off) chRows = (long)((availF - off) / NPH) / 128 * 128;
  if (chRows < 128) chRows = 128;              // assume ws is at least ~25MB
  int CH = (int)(chRows > (long)NBS ? (long)NBS : chRows);
  float* premax = wsf + off;

  // ---- init state ----
  init_kernel<<<NB, 256, 0, stream>>>(mask, hbuf, cbuf, sprev, eprev);

  // ---- hoist premod = mod @ W1[:, :400]^T per head ----
  if (hoisted){
    for (int net=0; net<2; net++)
      gemm_nt<<<dim3(NBS/128, NPH/128), 256, 0, stream>>>(mod, NM, W1[net], NM+NH, NM,
                                                          premod[net], NPH);
  }

  // helper: out[rows,H] = max_p( A@Wt + bias )  via chunked premax buffer
  auto maxout_gemm = [&](const float* A, int lda, int kdim, const float* W, int ldw,
                         const float* bias, int perB, float* outBuf){
    for (int r0=0; r0<NBS; r0+=CH){
      int rows = (NBS - r0) < CH ? (NBS - r0) : CH;
      gemm_nt<<<dim3(rows/128, NPH/128), 256, 0, stream>>>(A + (size_t)r0*lda, lda,
                                                           W, ldw, kdim, premax, NPH);
      maxp_kernel<<<rows, 256, 0, stream>>>(premax, bias, perB, r0, outBuf);
    }
  };

  for (int t=0; t<NT; t++){
    lstm_kernel<<<NB, 256, 0, stream>>>(mod, sprev, eprev, Wih, Whh, bih, bhh, hbuf, cbuf);
    for (int net=0; net<2; net++){
      // net 0: start head (updates sprev); net 1: end head (updates eprev)
      r_prer_kernel<<<NB, 256, 0, stream>>>(mod, sprev, eprev, hbuf,
                                            rW[net], W1[net], b1[net], prer);
      if (hoisted){
        maxp_kernel<<<NBS, 256, 0, stream>>>(premod[net], prer, 1, 0, m1);
      } else {
        maxout_gemm(mod, NM, NM, W1[net], NM+NH, prer, 1, m1);
      }
      maxout_gemm(m1, NH, NH, W2[net], NH, b2[net], 0, m2);
      logits_kernel<<<NB, 256, 0, stream>>>(m1, m2, W3[net], b3[net], mask,
                                            out[net], t, net==0 ? sprev : eprev);
    }
  }
}

// Round 2
// 5057.632 us; speedup vs baseline: 1.5701x; 1.5701x over previous
//
#include <hip/hip_runtime.h>
#include <math.h>

#define NB 32
#define NS 400
#define NM 400
#define NH 200
#define NP 16
#define NT 4
#define NBS (NB*NS)          // 12800
#define NPH (NP*NH)          // 3200
#define NX  (2*NM)           // 800
#define NG  (4*NH)           // 800
#define NR  (2*NM+NH)        // 1000
#define K1  1280             // m1 GEMM K' (3*400 padded to /32)
#define K2  640              // m2 GEMM K' (3*200 padded to /32)

typedef __attribute__((ext_vector_type(8))) short short8v;
typedef __attribute__((ext_vector_type(4))) float f32x4;
typedef __attribute__((ext_vector_type(4))) unsigned short us4;
typedef unsigned short ushort;

__device__ __forceinline__ float sigf(float x){ return 1.0f/(1.0f+expf(-x)); }

__device__ __forceinline__ ushort f2bf(float x){
  union{float f; unsigned u;} v; v.f=x;
  unsigned r = v.u + 0x7fffu + ((v.u>>16)&1u);
  return (ushort)(r>>16);
}
__device__ __forceinline__ float bf2f(ushort u){
  union{float f; unsigned v;} x; x.v = ((unsigned)u)<<16; return x.f;
}

// ---------------- init ----------------
__global__ __launch_bounds__(256) void init_kernel(const float* __restrict__ mask,
    float* __restrict__ h, float* __restrict__ c,
    int* __restrict__ sprev, int* __restrict__ eprev){
  int b = blockIdx.x, tid = threadIdx.x;
  __shared__ float red[256];
  float s = 0.f;
  for (int i=tid;i<NS;i+=256) s += mask[(size_t)b*NS+i];
  red[tid]=s; __syncthreads();
  for (int st=128;st>0;st>>=1){ if(tid<st) red[tid]+=red[tid+st]; __syncthreads(); }
  if (tid==0){ sprev[b]=0; eprev[b]=(int)red[0]-1; }
  for (int i=tid;i<NH;i+=256){ h[(size_t)b*NH+i]=0.f; c[(size_t)b*NH+i]=0.f; }
}

// ---------------- conversions / prep ----------------
// mod [12800][400] f32 -> modExp [12800][1280] bf16 as [hi|lo|hi|pad]
__global__ __launch_bounds__(256) void conv_mod_k(const float* __restrict__ in, ushort* __restrict__ out){
  for (size_t i = (size_t)blockIdx.x*256+threadIdx.x; i < (size_t)NBS*NM; i += (size_t)gridDim.x*256){
    int r = (int)(i/NM), k = (int)(i%NM);
    float x = in[i];
    ushort h = f2bf(x); ushort lo = f2bf(x - bf2f(h));
    ushort* o = out + (size_t)r*K1;
    o[k]=h; o[NM+k]=lo; o[2*NM+k]=h;
  }
}
// W1 [3200][600] -> W1exp [3200][1280] rows permuted j'=h*16+p, [hi|hi|lo|pad]; only cols 0..400
__global__ __launch_bounds__(256) void conv_w1_k(const float* __restrict__ in, ushort* __restrict__ out){
  for (size_t i = (size_t)blockIdx.x*256+threadIdx.x; i < (size_t)NPH*NM; i += (size_t)gridDim.x*256){
    int j = (int)(i/NM), k = (int)(i%NM);
    int jp = (j%NH)*NP + j/NH;
    float x = in[(size_t)j*(NM+NH)+k];
    ushort h = f2bf(x); ushort lo = f2bf(x - bf2f(h));
    ushort* o = out + (size_t)jp*K1;
    o[k]=h; o[NM+k]=h; o[2*NM+k]=lo;
  }
}
// W2 [3200][200] -> W2exp [3200][640] rows permuted, [hi|hi|lo|pad]
__global__ __launch_bounds__(256) void conv_w2_k(const float* __restrict__ in, ushort* __restrict__ out){
  for (size_t i = (size_t)blockIdx.x*256+threadIdx.x; i < (size_t)NPH*NH; i += (size_t)gridDim.x*256){
    int j = (int)(i/NH), k = (int)(i%NH);
    int jp = (j%NH)*NP + j/NH;
    float x = in[(size_t)j*NH+k];
    ushort h = f2bf(x); ushort lo = f2bf(x - bf2f(h));
    ushort* o = out + (size_t)jp*K2;
    o[k]=h; o[NH+k]=h; o[2*NH+k]=lo;
  }
}
__global__ __launch_bounds__(256) void permb2_k(const float* __restrict__ in, float* __restrict__ out){
  int i = blockIdx.x*256+threadIdx.x;
  if (i < NPH) out[(i%NH)*NP + i/NH] = in[i];
}
// zero a pad region: rows x width at col start, row stride
__global__ __launch_bounds__(256) void pad_zero_k(ushort* __restrict__ p, int stride, int start, int width, int rows){
  for (size_t i = (size_t)blockIdx.x*256+threadIdx.x; i < (size_t)rows*width; i += (size_t)gridDim.x*256){
    int r = (int)(i/width), j = (int)(i%width);
    p[(size_t)r*stride + start + j] = 0;
  }
}

// ---------------- LSTM cell ----------------
__global__ __launch_bounds__(256) void lstm_kernel(const float* __restrict__ mod,
    const int* __restrict__ sprev, const int* __restrict__ eprev,
    const float* __restrict__ Wih, const float* __restrict__ Whh,
    const float* __restrict__ bih, const float* __restrict__ bhh,
    float* __restrict__ h, float* __restrict__ c){
  int b=blockIdx.x, tid=threadIdx.x;
  __shared__ float xs[NX];
  __shared__ float hs[NH];
  __shared__ float gs[NG];
  const float* us = mod + ((size_t)b*NS + sprev[b])*NM;
  const float* ue = mod + ((size_t)b*NS + eprev[b])*NM;
  for (int i=tid;i<NM;i+=256){ xs[i]=us[i]; xs[NM+i]=ue[i]; }
  for (int i=tid;i<NH;i+=256) hs[i]=h[(size_t)b*NH+i];
  __syncthreads();
  for (int j=tid;j<NG;j+=256){
    float acc = bih[j]+bhh[j];
    const float4* wr=(const float4*)(Wih+(size_t)j*NX);
    #pragma unroll 4
    for (int k=0;k<NX/4;k++){ float4 w=wr[k];
      acc+=xs[4*k]*w.x+xs[4*k+1]*w.y+xs[4*k+2]*w.z+xs[4*k+3]*w.w; }
    const float4* wh=(const float4*)(Whh+(size_t)j*NH);
    #pragma unroll 4
    for (int k=0;k<NH/4;k++){ float4 w=wh[k];
      acc+=hs[4*k]*w.x+hs[4*k+1]*w.y+hs[4*k+2]*w.z+hs[4*k+3]*w.w; }
    gs[j]=acc;
  }
  __syncthreads();
  for (int j=tid;j<NH;j+=256){
    float iv=gs[j], fv=gs[NH+j], gv=gs[2*NH+j], ov=gs[3*NH+j];
    float c2 = sigf(fv)*c[(size_t)b*NH+j] + sigf(iv)*tanhf(gv);
    c[(size_t)b*NH+j]=c2;
    h[(size_t)b*NH+j]=sigf(ov)*tanhf(c2);
  }
}

// ---- r = tanh([h,us,ue]@rW^T); prer[b][h*16+p] = b1[j] + r@W1[:,400:600]^T ----
__global__ __launch_bounds__(256) void r_prer_kernel(const float* __restrict__ mod,
    const int* __restrict__ sprev, const int* __restrict__ eprev,
    const float* __restrict__ h,
    const float* __restrict__ rW, const float* __restrict__ W1,
    const float* __restrict__ b1, float* __restrict__ prer){
  int b=blockIdx.x, tid=threadIdx.x;
  __shared__ float zs[NR];
  __shared__ float rsh[NH];
  for (int i=tid;i<NH;i+=256) zs[i]=h[(size_t)b*NH+i];
  const float* us = mod + ((size_t)b*NS + sprev[b])*NM;
  const float* ue = mod + ((size_t)b*NS + eprev[b])*NM;
  for (int i=tid;i<NM;i+=256){ zs[NH+i]=us[i]; zs[NH+NM+i]=ue[i]; }
  __syncthreads();
  for (int j=tid;j<NH;j+=256){
    float acc=0.f;
    const float4* wr=(const float4*)(rW+(size_t)j*NR);
    #pragma unroll 4
    for (int k=0;k<NR/4;k++){ float4 w=wr[k];
      acc+=zs[4*k]*w.x+zs[4*k+1]*w.y+zs[4*k+2]*w.z+zs[4*k+3]*w.w; }
    rsh[j]=tanhf(acc);
  }
  __syncthreads();
  for (int j=tid;j<NPH;j+=256){
    float acc=b1[j];
    const float4* w=(const float4*)(W1+(size_t)j*(NM+NH)+NM);
    #pragma unroll 4
    for (int k=0;k<NH/4;k++){ float4 ww=w[k];
      acc+=rsh[4*k]*ww.x+rsh[4*k+1]*ww.y+rsh[4*k+2]*ww.z+rsh[4*k+3]*ww.w; }
    prer[(size_t)b*NPH + (j%NH)*NP + j/NH]=acc;
  }
}

// ------------- fused bf16-split GEMM + bias + max-over-P epilogue -------------
// C_pre[i][j'] = sum_k A'[i][k] W'[j'][k]  (j' = h*16+p permuted)
// out[i][h] = max_p (C_pre[i][h*16+p] + bias[...][h*16+p])
// MODE 0: bias = prer per-b (b=i/400); out = m1exp ushort[12800][640] ([hi|lo|hi|pad])
// MODE 1: bias = b2perm (uniform); out = m2 float[12800][200]
template<int MODE>
__global__ __launch_bounds__(256) void gemm_fused(
    const ushort* __restrict__ A, const ushort* __restrict__ W, int ldk,
    const float* __restrict__ bias, void* __restrict__ outp){
  __shared__ __align__(16) ushort As[128*32];
  __shared__ __align__(16) ushort Bs[128*32];
  __shared__ float biasLds[2][128];
  __shared__ float outT[128][8];
  const int tid = threadIdx.x;
  const int i0 = blockIdx.x*128, j0 = blockIdx.y*128;
  const int b0 = i0/NS;
  if (MODE==0){
    if (tid<128) biasLds[0][tid] = bias[(size_t)b0*NPH + j0 + tid];
    else { int b1r = (i0+127)/NS; biasLds[1][tid-128] = bias[(size_t)b1r*NPH + j0 + (tid-128)]; }
  } else {
    if (tid<128) biasLds[0][tid] = bias[j0+tid];
  }
  f32x4 acc[4][4] = {};
  const int l = tid&63, w = tid>>6;
  const int wr = w>>1, wc = w&1;             // 2x2 waves, 64x64 each
  const int srow = tid>>2, slot = tid&3;     // staging: 4 lanes/row
  const int fr = l&15, fk = l>>4;            // fragment row/k-group
  const int ksteps = ldk>>5;
  for (int kt=0; kt<ksteps; kt++){
    if (kt) __syncthreads();
    #pragma unroll
    for (int r=0;r<2;r++){
      int row = r*64 + srow;
      int ss  = slot ^ (row&3);              // pre-swizzled global slot
      const ushort* ga = A + (size_t)(i0+row)*ldk + kt*32 + ss*8;
      const ushort* gb = W + (size_t)(j0+row)*ldk + kt*32 + ss*8;
      __builtin_amdgcn_global_load_lds((const __attribute__((address_space(1))) void*)ga,
          (__attribute__((address_space(3))) void*)(As + row*32 + slot*8), 16, 0, 0);
      __builtin_amdgcn_global_load_lds((const __attribute__((address_space(1))) void*)gb,
          (__attribute__((address_space(3))) void*)(Bs + row*32 + slot*8), 16, 0, 0);
    }
    __syncthreads();
    short8v af[4], bf[4];
    #pragma unroll
    for (int m=0;m<4;m++){
      int row = wr*64 + m*16 + fr;
      int sl = fk ^ (row&3);
      af[m] = *(const short8v*)(As + row*32 + sl*8);
    }
    #pragma unroll
    for (int n=0;n<4;n++){
      int row = wc*64 + n*16 + fr;
      int sl = fk ^ (row&3);
      bf[n] = *(const short8v*)(Bs + row*32 + sl*8);
    }
    #pragma unroll
    for (int m=0;m<4;m++)
      #pragma unroll
      for (int n=0;n<4;n++)
        acc[m][n] = __builtin_amdgcn_mfma_f32_16x16x32_bf16(af[m], bf[n], acc[m][n], 0,0,0);
  }
  __syncthreads();
  // epilogue: bias + max over the 16 cols (=p) of each 16x16 fragment
  const int blim = (b0+1)*NS;
  #pragma unroll
  for (int m=0;m<4;m++){
    #pragma unroll
    for (int n=0;n<4;n++){
      int colL = wc*64 + n*16 + fr;
      int rbase = wr*64 + m*16 + fk*4;
      #pragma unroll
      for (int reg=0; reg<4; reg++){
        int rowL = rbase + reg;
        float bv;
        if (MODE==0) bv = ((i0+rowL) >= blim) ? biasLds[1][colL] : biasLds[0][colL];
        else bv = biasLds[0][colL];
        float v = acc[m][n][reg] + bv;
        v = fmaxf(v, __shfl_xor(v,1));
        v = fmaxf(v, __shfl_xor(v,2));
        v = fmaxf(v, __shfl_xor(v,4));
        v = fmaxf(v, __shfl_xor(v,8));
        if (fr==0) outT[rowL][wc*4+n] = v;
      }
    }
  }
  __syncthreads();
  {
    int rowL = tid>>1;
    int c4 = (tid&1)*4;
    int absrow = i0 + rowL;
    int hg0 = (j0>>4) + c4;     // global h start for this thread's 4 cols
    float v0=outT[rowL][c4], v1=outT[rowL][c4+1], v2=outT[rowL][c4+2], v3=outT[rowL][c4+3];
    if (MODE==0){
      ushort* o = (ushort*)outp + (size_t)absrow*K2 + hg0;
      ushort h0=f2bf(v0), h1=f2bf(v1), h2=f2bf(v2), h3=f2bf(v3);
      ushort l0=f2bf(v0-bf2f(h0)), l1=f2bf(v1-bf2f(h1)), l2=f2bf(v2-bf2f(h2)), l3=f2bf(v3-bf2f(h3));
      *(us4*)(o)        = (us4){h0,h1,h2,h3};
      *(us4*)(o+NH)     = (us4){l0,l1,l2,l3};
      *(us4*)(o+2*NH)   = (us4){h0,h1,h2,h3};
    } else {
      float* o = (float*)outp + (size_t)absrow*NH + hg0;
      *(f32x4*)o = (f32x4){v0,v1,v2,v3};
    }
  }
}

// --------- logits (maxout-3) + mask + log_softmax + argmax; one block per b ---------
__global__ __launch_bounds__(256) void logits_kernel(const ushort* __restrict__ m1e,
    const float* __restrict__ m2, const float* __restrict__ W3, const float* __restrict__ b3,
    const float* __restrict__ mask, float* __restrict__ out, int t, int* __restrict__ prevIdx){
  int b=blockIdx.x, tid=threadIdx.x;
  __shared__ float lg[NS];
  for (int s=tid; s<NS; s+=256){
    const ushort* a = m1e + (size_t)(b*NS+s)*K2;
    const float4* d = (const float4*)(m2 + (size_t)(b*NS+s)*NH);
    float acc[NP];
    #pragma unroll
    for (int p=0;p<NP;p++) acc[p]=b3[p];
    for (int k=0;k<NH/4;k++){
      us4 hv = *(const us4*)(a + 4*k);
      us4 lv = *(const us4*)(a + NH + 4*k);
      float4 dv = d[k];
      float a0=bf2f(hv.x)+bf2f(lv.x), a1=bf2f(hv.y)+bf2f(lv.y);
      float a2=bf2f(hv.z)+bf2f(lv.z), a3=bf2f(hv.w)+bf2f(lv.w);
      #pragma unroll
      for (int p=0;p<NP;p++){
        const float* wp = W3 + p*(2*NH) + 4*k;
        acc[p] += a0*wp[0]+a1*wp[1]+a2*wp[2]+a3*wp[3];
        const float* w2 = wp + NH;
        acc[p] += dv.x*w2[0]+dv.y*w2[1]+dv.z*w2[2]+dv.w*w2[3];
      }
    }
    float best=acc[0];
    #pragma unroll
    for (int p=1;p<NP;p++) best=fmaxf(best,acc[p]);
    lg[s] = (mask[(size_t)b*NS+s] > 0.f) ? best : -1e30f;
  }
  __syncthreads();
  __shared__ float rv[256]; __shared__ int ri[256]; __shared__ float sv[256];
  float bv=-INFINITY; int bi=NS;
  for (int s=tid;s<NS;s+=256){ float v=lg[s]; if (v>bv){bv=v;bi=s;} }
  rv[tid]=bv; ri[tid]=bi; __syncthreads();
  for (int st=128;st>0;st>>=1){
    if (tid<st){
      float v2=rv[tid+st]; int i2=ri[tid+st];
      if (v2>rv[tid] || (v2==rv[tid] && i2<ri[tid])){ rv[tid]=v2; ri[tid]=i2; }
    }
    __syncthreads();
  }
  float mx = rv[0];
  float ps=0.f;
  for (int s=tid;s<NS;s+=256) ps += expf(lg[s]-mx);
  sv[tid]=ps; __syncthreads();
  for (int st=128;st>0;st>>=1){ if (tid<st) sv[tid]+=sv[tid+st]; __syncthreads(); }
  float lse = mx + logf(sv[0]);
  for (int s=tid;s<NS;s+=256) out[((size_t)b*NT + t)*NS + s] = lg[s]-lse;
  if (tid==0) prevIdx[b]=ri[0];
}

// =============================== host ===============================
extern "C" void kernel_launch(void* const* d_in, const int* in_sizes, int n_in,
                              void* d_out, int out_size, void* d_ws, size_t ws_size,
                              hipStream_t stream){
  const float* mod  = (const float*)d_in[1];
  const float* mask = (const float*)d_in[2];
  const float* Wih  = (const float*)d_in[3];
  const float* Whh  = (const float*)d_in[4];
  const float* bih  = (const float*)d_in[5];
  const float* bhh  = (const float*)d_in[6];
  const float* rW[2] = {(const float*)d_in[7],  (const float*)d_in[14]};
  const float* W1[2] = {(const float*)d_in[8],  (const float*)d_in[15]};
  const float* b1[2] = {(const float*)d_in[9],  (const float*)d_in[16]};
  const float* W2[2] = {(const float*)d_in[10], (const float*)d_in[17]};
  const float* b2[2] = {(const float*)d_in[11], (const float*)d_in[18]};
  const float* W3[2] = {(const float*)d_in[12], (const float*)d_in[19]};
  const float* b3[2] = {(const float*)d_in[13], (const float*)d_in[20]};
  float* out[2];
  out[0] = (float*)d_out;
  out[1] = out[0] + (size_t)NB*NT*NS;

  float* wsf = (float*)d_ws;
  size_t off = 0;
  auto carve = [&](size_t n)->size_t{ size_t o=off; off += (n + 63) & ~(size_t)63; return o; };
  float* hbuf   = wsf + carve((size_t)NB*NH);
  float* cbuf   = wsf + carve((size_t)NB*NH);
  float* prer   = wsf + carve((size_t)NB*NPH);
  int*   sprev  = (int*)(wsf + carve(128));
  int*   eprev  = sprev + 32;
  float* m2f    = wsf + carve((size_t)NBS*NH);
  float* b2p[2] = {wsf + carve(NPH), wsf + carve(NPH)};
  ushort* modExp   = (ushort*)(wsf + carve((size_t)NBS*K1/2));
  ushort* W1exp[2] = {(ushort*)(wsf + carve((size_t)NPH*K1/2)),
                      (ushort*)(wsf + carve((size_t)NPH*K1/2))};
  ushort* W2exp[2] = {(ushort*)(wsf + carve((size_t)NPH*K2/2)),
                      (ushort*)(wsf + carve((size_t)NPH*K2/2))};
  ushort* m1exp    = (ushort*)(wsf + carve((size_t)NBS*K2/2));

  // ---- init + prep (every launch; deterministic) ----
  init_kernel<<<NB, 256, 0, stream>>>(mask, hbuf, cbuf, sprev, eprev);
  conv_mod_k<<<2048, 256, 0, stream>>>(mod, modExp);
  pad_zero_k<<<256, 256, 0, stream>>>(modExp, K1, 3*NM, K1-3*NM, NBS);
  pad_zero_k<<<256, 256, 0, stream>>>(m1exp, K2, 3*NH, K2-3*NH, NBS);
  for (int net=0; net<2; net++){
    conv_w1_k<<<2048, 256, 0, stream>>>(W1[net], W1exp[net]);
    pad_zero_k<<<64, 256, 0, stream>>>(W1exp[net], K1, 3*NM, K1-3*NM, NPH);
    conv_w2_k<<<1024, 256, 0, stream>>>(W2[net], W2exp[net]);
    pad_zero_k<<<64, 256, 0, stream>>>(W2exp[net], K2, 3*NH, K2-3*NH, NPH);
    permb2_k<<<(NPH+255)/256, 256, 0, stream>>>(b2[net], b2p[net]);
  }

  dim3 ggrid(NBS/128, NPH/128);
  for (int t=0; t<NT; t++){
    lstm_kernel<<<NB, 256, 0, stream>>>(mod, sprev, eprev, Wih, Whh, bih, bhh, hbuf, cbuf);
    for (int net=0; net<2; net++){
      r_prer_kernel<<<NB, 256, 0, stream>>>(mod, sprev, eprev, hbuf,
                                            rW[net], W1[net], b1[net], prer);
      gemm_fused<0><<<ggrid, 256, 0, stream>>>(modExp, W1exp[net], K1, prer, (void*)m1exp);
      gemm_fused<1><<<ggrid, 256, 0, stream>>>(m1exp, W2exp[net], K2, b2p[net], (void*)m2f);
      logits_kernel<<<NB, 256, 0, stream>>>(m1exp, m2f, W3[net], b3[net], mask,
                                            out[net], t, net==0 ? sprev : eprev);
    }
  }
}

// Round 3
// 3124.363 us; speedup vs baseline: 2.5416x; 1.6188x over previous
//
#include <hip/hip_runtime.h>
#include <math.h>

#define NB 32
#define NS 400
#define NM 400
#define NH 200
#define NP 16
#define NT 4
#define NBS (NB*NS)          // 12800
#define NPH (NP*NH)          // 3200
#define NX  (2*NM)           // 800
#define NG  (4*NH)           // 800
#define NR  (2*NM+NH)        // 1000
#define K1  1280             // m1 GEMM K' (3*400 padded to /32)
#define K2  640              // m2 GEMM K' (3*200 padded to /32)

typedef __attribute__((ext_vector_type(8))) short short8v;
typedef __attribute__((ext_vector_type(4))) float f32x4;
typedef __attribute__((ext_vector_type(4))) unsigned short us4;
typedef unsigned short ushort;

__device__ __forceinline__ float sigf(float x){ return 1.0f/(1.0f+expf(-x)); }

__device__ __forceinline__ ushort f2bf(float x){
  union{float f; unsigned u;} v; v.f=x;
  unsigned r = v.u + 0x7fffu + ((v.u>>16)&1u);
  return (ushort)(r>>16);
}
__device__ __forceinline__ float bf2f(ushort u){
  union{float f; unsigned v;} x; x.v = ((unsigned)u)<<16; return x.f;
}
__device__ __forceinline__ float wave_sum(float v){
  #pragma unroll
  for (int o=32;o>0;o>>=1) v += __shfl_xor(v, o);
  return v;
}

// ---------------- init: h=c=0, sprev=0, eprev=sum(mask)-1 ----------------
__global__ __launch_bounds__(256) void init_kernel(const float* __restrict__ mask,
    float* __restrict__ h, float* __restrict__ c,
    int* __restrict__ sprev, int* __restrict__ eprev){
  int b = blockIdx.x, tid = threadIdx.x;
  __shared__ float red[256];
  float s = 0.f;
  for (int i=tid;i<NS;i+=256) s += mask[(size_t)b*NS+i];
  red[tid]=s; __syncthreads();
  for (int st=128;st>0;st>>=1){ if(tid<st) red[tid]+=red[tid+st]; __syncthreads(); }
  if (tid==0){ sprev[b]=0; eprev[b]=(int)red[0]-1; }
  for (int i=tid;i<NH;i+=256){ h[(size_t)b*NH+i]=0.f; c[(size_t)b*NH+i]=0.f; }
}

// ---------------- conversions / prep ----------------
__global__ __launch_bounds__(256) void conv_mod_k(const float* __restrict__ in, ushort* __restrict__ out){
  for (size_t i = (size_t)blockIdx.x*256+threadIdx.x; i < (size_t)NBS*NM; i += (size_t)gridDim.x*256){
    int r = (int)(i/NM), k = (int)(i%NM);
    float x = in[i];
    ushort h = f2bf(x); ushort lo = f2bf(x - bf2f(h));
    ushort* o = out + (size_t)r*K1;
    o[k]=h; o[NM+k]=lo; o[2*NM+k]=h;
  }
}
__global__ __launch_bounds__(256) void conv_w1_k(const float* __restrict__ in, ushort* __restrict__ out){
  for (size_t i = (size_t)blockIdx.x*256+threadIdx.x; i < (size_t)NPH*NM; i += (size_t)gridDim.x*256){
    int j = (int)(i/NM), k = (int)(i%NM);
    int jp = (j%NH)*NP + j/NH;
    float x = in[(size_t)j*(NM+NH)+k];
    ushort h = f2bf(x); ushort lo = f2bf(x - bf2f(h));
    ushort* o = out + (size_t)jp*K1;
    o[k]=h; o[NM+k]=h; o[2*NM+k]=lo;
  }
}
__global__ __launch_bounds__(256) void conv_w2_k(const float* __restrict__ in, ushort* __restrict__ out){
  for (size_t i = (size_t)blockIdx.x*256+threadIdx.x; i < (size_t)NPH*NH; i += (size_t)gridDim.x*256){
    int j = (int)(i/NH), k = (int)(i%NH);
    int jp = (j%NH)*NP + j/NH;
    float x = in[(size_t)j*NH+k];
    ushort h = f2bf(x); ushort lo = f2bf(x - bf2f(h));
    ushort* o = out + (size_t)jp*K2;
    o[k]=h; o[NH+k]=h; o[2*NH+k]=lo;
  }
}
// W1rT[k][jp] = W1[j][400+k], jp-permuted; k<200, jp<3200
__global__ __launch_bounds__(256) void conv_w1r_k(const float* __restrict__ in, float* __restrict__ out){
  for (size_t i = (size_t)blockIdx.x*256+threadIdx.x; i < (size_t)NH*NPH; i += (size_t)gridDim.x*256){
    int k = (int)(i/NPH), jp = (int)(i%NPH);
    int hh = jp>>4, p = jp&15, j = p*NH + hh;
    out[i] = in[(size_t)j*(NM+NH) + NM + k];
  }
}
__global__ __launch_bounds__(256) void permv_k(const float* __restrict__ in, float* __restrict__ out){
  int i = blockIdx.x*256+threadIdx.x;
  if (i < NPH) out[(i%NH)*NP + i/NH] = in[i];
}
__global__ __launch_bounds__(256) void pad_zero_k(ushort* __restrict__ p, int stride, int start, int width, int rows){
  for (size_t i = (size_t)blockIdx.x*256+threadIdx.x; i < (size_t)rows*width; i += (size_t)gridDim.x*256){
    int r = (int)(i/width), j = (int)(i%width);
    p[(size_t)r*stride + start + j] = 0;
  }
}

// ---------------- LSTM: gates (wave per gate) + update ----------------
__global__ __launch_bounds__(256) void lstm_gates(const float* __restrict__ mod,
    const int* __restrict__ sprev, const int* __restrict__ eprev,
    const float* __restrict__ h,
    const float* __restrict__ Wih, const float* __restrict__ Whh,
    const float* __restrict__ bih, const float* __restrict__ bhh,
    float* __restrict__ gs){
  int b=blockIdx.x, tid=threadIdx.x;
  __shared__ float xs[NX+NH];
  const float* us = mod + ((size_t)b*NS + sprev[b])*NM;
  const float* ue = mod + ((size_t)b*NS + eprev[b])*NM;
  for (int i=tid;i<NM;i+=256){ xs[i]=us[i]; xs[NM+i]=ue[i]; }
  for (int i=tid;i<NH;i+=256) xs[NX+i]=h[(size_t)b*NH+i];
  __syncthreads();
  int w=tid>>6, lane=tid&63;
  int j = blockIdx.y*4 + w;                 // gridDim.y = 200 -> j < 800
  const float* wih = Wih + (size_t)j*NX;
  const float* whh = Whh + (size_t)j*NH;
  float acc=0.f;
  for (int k=lane;k<NX;k+=64) acc += xs[k]*wih[k];
  for (int k=lane;k<NH;k+=64) acc += xs[NX+k]*whh[k];
  acc = wave_sum(acc);
  if (lane==0) gs[(size_t)b*NG+j] = acc + bih[j] + bhh[j];
}
__global__ __launch_bounds__(256) void lstm_update(const float* __restrict__ gs,
    float* __restrict__ h, float* __restrict__ c){
  int b=blockIdx.x, j=threadIdx.x;
  if (j<NH){
    float iv=gs[(size_t)b*NG+j], fv=gs[(size_t)b*NG+NH+j];
    float gv=gs[(size_t)b*NG+2*NH+j], ov=gs[(size_t)b*NG+3*NH+j];
    float c2 = sigf(fv)*c[(size_t)b*NH+j] + sigf(iv)*tanhf(gv);
    c[(size_t)b*NH+j]=c2;
    h[(size_t)b*NH+j]=sigf(ov)*tanhf(c2);
  }
}

// ---------------- r = tanh([h,us,ue]@rW^T), wave per output ----------------
__global__ __launch_bounds__(256) void r_kernel(const float* __restrict__ mod,
    const int* __restrict__ sprev, const int* __restrict__ eprev,
    const float* __restrict__ h, const float* __restrict__ rW,
    float* __restrict__ rbuf){
  int b=blockIdx.x, tid=threadIdx.x;
  __shared__ float zs[NR];
  const float* us = mod + ((size_t)b*NS + sprev[b])*NM;
  const float* ue = mod + ((size_t)b*NS + eprev[b])*NM;
  for (int i=tid;i<NH;i+=256) zs[i]=h[(size_t)b*NH+i];
  for (int i=tid;i<NM;i+=256){ zs[NH+i]=us[i]; zs[NH+NM+i]=ue[i]; }
  __syncthreads();
  int w=tid>>6, lane=tid&63;
  int j = blockIdx.y*4 + w;                 // gridDim.y = 50 -> j < 200
  const float* wr = rW + (size_t)j*NR;
  float acc=0.f;
  for (int k=lane;k<NR;k+=64) acc += zs[k]*wr[k];
  acc = wave_sum(acc);
  if (lane==0) rbuf[(size_t)b*NH+j] = tanhf(acc);
}

// ---------------- prer[b][jp] = b1p[jp] + sum_k r[b][k]*W1rT[k][jp] ----------------
__global__ __launch_bounds__(256) void prer_kernel(const float* __restrict__ rbuf,
    const float* __restrict__ W1rT, const float* __restrict__ b1p,
    float* __restrict__ prer){
  int b=blockIdx.x, tid=threadIdx.x;
  __shared__ float rs[NH];
  if (tid < NH) rs[tid] = rbuf[(size_t)b*NH+tid];
  __syncthreads();
  int jp = blockIdx.y*256 + tid;
  if (jp < NPH){
    float acc = b1p[jp];
    #pragma unroll 8
    for (int k=0;k<NH;k++) acc += rs[k]*W1rT[(size_t)k*NPH + jp];
    prer[(size_t)b*NPH + jp] = acc;
  }
}

// ------------- fused bf16-split GEMM + bias + max-over-P, 2-phase dbuf -------------
template<int MODE>
__global__ __launch_bounds__(256) void gemm_fused(
    const ushort* __restrict__ A, const ushort* __restrict__ W, int ldk,
    const float* __restrict__ bias, void* __restrict__ outp){
  __shared__ __align__(16) ushort As[2][128*32];
  __shared__ __align__(16) ushort Bs[2][128*32];
  __shared__ float biasLds[2][128];
  __shared__ float outT[128][8];
  const int tid = threadIdx.x;
  const int i0 = blockIdx.x*128, j0 = blockIdx.y*128;
  const int b0 = i0/NS;
  if (MODE==0){
    if (tid<128) biasLds[0][tid] = bias[(size_t)b0*NPH + j0 + tid];
    else { int b1r = (i0+127)/NS; biasLds[1][tid-128] = bias[(size_t)b1r*NPH + j0 + (tid-128)]; }
  } else {
    if (tid<128) biasLds[0][tid] = bias[j0+tid];
  }
  const int l = tid&63, w = tid>>6;
  const int wr = w>>1, wc = w&1;             // 2x2 waves, 64x64 each
  const int srow = tid>>2, slot = tid&3;     // staging: 4 lanes/row
  const int fr = l&15, fk = l>>4;            // fragment row/k-group
  const int ksteps = ldk>>5;
  auto stage = [&](int buf, int kt){
    #pragma unroll
    for (int r=0;r<2;r++){
      int row = r*64 + srow;
      int ss  = slot ^ ((row>>1)&3);         // pre-swizzled global slot (2-way-free)
      const ushort* ga = A + (size_t)(i0+row)*ldk + kt*32 + ss*8;
      const ushort* gb = W + (size_t)(j0+row)*ldk + kt*32 + ss*8;
      __builtin_amdgcn_global_load_lds((const __attribute__((address_space(1))) void*)ga,
          (__attribute__((address_space(3))) void*)(&As[buf][row*32 + slot*8]), 16, 0, 0);
      __builtin_amdgcn_global_load_lds((const __attribute__((address_space(1))) void*)gb,
          (__attribute__((address_space(3))) void*)(&Bs[buf][row*32 + slot*8]), 16, 0, 0);
    }
  };
  f32x4 acc[4][4] = {};
  stage(0, 0);
  __syncthreads();
  int cur = 0;
  for (int kt=0; kt<ksteps; kt++){
    if (kt+1 < ksteps) stage(cur^1, kt+1);
    short8v af[4], bf[4];
    #pragma unroll
    for (int m=0;m<4;m++){
      int row = wr*64 + m*16 + fr;
      int sl = fk ^ ((row>>1)&3);
      af[m] = *(const short8v*)(&As[cur][row*32 + sl*8]);
    }
    #pragma unroll
    for (int n=0;n<4;n++){
      int row = wc*64 + n*16 + fr;
      int sl = fk ^ ((row>>1)&3);
      bf[n] = *(const short8v*)(&Bs[cur][row*32 + sl*8]);
    }
    #pragma unroll
    for (int m=0;m<4;m++)
      #pragma unroll
      for (int n=0;n<4;n++)
        acc[m][n] = __builtin_amdgcn_mfma_f32_16x16x32_bf16(af[m], bf[n], acc[m][n], 0,0,0);
    __syncthreads();
    cur ^= 1;
  }
  // epilogue: bias + max over the 16 cols (=p) of each 16x16 fragment
  const int blim = (b0+1)*NS;
  #pragma unroll
  for (int m=0;m<4;m++){
    #pragma unroll
    for (int n=0;n<4;n++){
      int colL = wc*64 + n*16 + fr;
      int rbase = wr*64 + m*16 + fk*4;
      #pragma unroll
      for (int reg=0; reg<4; reg++){
        int rowL = rbase + reg;
        float bv;
        if (MODE==0) bv = ((i0+rowL) >= blim) ? biasLds[1][colL] : biasLds[0][colL];
        else bv = biasLds[0][colL];
        float v = acc[m][n][reg] + bv;
        v = fmaxf(v, __shfl_xor(v,1));
        v = fmaxf(v, __shfl_xor(v,2));
        v = fmaxf(v, __shfl_xor(v,4));
        v = fmaxf(v, __shfl_xor(v,8));
        if (fr==0) outT[rowL][wc*4+n] = v;
      }
    }
  }
  __syncthreads();
  {
    int rowL = tid>>1;
    int c4 = (tid&1)*4;
    int absrow = i0 + rowL;
    int hg0 = (j0>>4) + c4;
    float v0=outT[rowL][c4], v1=outT[rowL][c4+1], v2=outT[rowL][c4+2], v3=outT[rowL][c4+3];
    if (MODE==0){
      ushort* o = (ushort*)outp + (size_t)absrow*K2 + hg0;
      ushort h0=f2bf(v0), h1=f2bf(v1), h2=f2bf(v2), h3=f2bf(v3);
      ushort l0=f2bf(v0-bf2f(h0)), l1=f2bf(v1-bf2f(h1)), l2=f2bf(v2-bf2f(h2)), l3=f2bf(v3-bf2f(h3));
      *(us4*)(o)        = (us4){h0,h1,h2,h3};
      *(us4*)(o+NH)     = (us4){l0,l1,l2,l3};
      *(us4*)(o+2*NH)   = (us4){h0,h1,h2,h3};
    } else {
      float* o = (float*)outp + (size_t)absrow*NH + hg0;
      *(f32x4*)o = (f32x4){v0,v1,v2,v3};
    }
  }
}

// --------- logits main: one thread per s, grid (NB, 2) ---------
__global__ __launch_bounds__(256) void logits_main(const ushort* __restrict__ m1e,
    const float* __restrict__ m2, const float* __restrict__ W3, const float* __restrict__ b3,
    const float* __restrict__ mask, float* __restrict__ lg){
  int b=blockIdx.x;
  int s=blockIdx.y*256+threadIdx.x;
  if (s >= NS) return;
  const ushort* a = m1e + (size_t)(b*NS+s)*K2;
  const float4* d = (const float4*)(m2 + (size_t)(b*NS+s)*NH);
  float acc[NP];
  #pragma unroll
  for (int p=0;p<NP;p++) acc[p]=b3[p];
  for (int k=0;k<NH/4;k++){
    us4 hv = *(const us4*)(a + 4*k);
    us4 lv = *(const us4*)(a + NH + 4*k);
    float4 dv = d[k];
    float a0=bf2f(hv.x)+bf2f(lv.x), a1=bf2f(hv.y)+bf2f(lv.y);
    float a2=bf2f(hv.z)+bf2f(lv.z), a3=bf2f(hv.w)+bf2f(lv.w);
    #pragma unroll
    for (int p=0;p<NP;p++){
      const float* wp = W3 + p*(2*NH) + 4*k;        // wave-uniform -> s_load
      acc[p] += a0*wp[0]+a1*wp[1]+a2*wp[2]+a3*wp[3];
      const float* w2 = wp + NH;
      acc[p] += dv.x*w2[0]+dv.y*w2[1]+dv.z*w2[2]+dv.w*w2[3];
    }
  }
  float best=acc[0];
  #pragma unroll
  for (int p=1;p<NP;p++) best=fmaxf(best,acc[p]);
  lg[(size_t)b*NS+s] = (mask[(size_t)b*NS+s] > 0.f) ? best : -1e30f;
}

// --------- logits finish: log_softmax + argmax; one block per b ---------
__global__ __launch_bounds__(256) void logits_fin(const float* __restrict__ lg,
    float* __restrict__ out, int t, int* __restrict__ prevIdx){
  int b=blockIdx.x, tid=threadIdx.x;
  __shared__ float rv[256]; __shared__ int ri[256]; __shared__ float sv[256];
  float bv=-INFINITY; int bi=NS;
  for (int s=tid;s<NS;s+=256){ float v=lg[(size_t)b*NS+s]; if (v>bv){bv=v;bi=s;} }
  rv[tid]=bv; ri[tid]=bi; __syncthreads();
  for (int st=128;st>0;st>>=1){
    if (tid<st){
      float v2=rv[tid+st]; int i2=ri[tid+st];
      if (v2>rv[tid] || (v2==rv[tid] && i2<ri[tid])){ rv[tid]=v2; ri[tid]=i2; }
    }
    __syncthreads();
  }
  float mx = rv[0];
  float ps=0.f;
  for (int s=tid;s<NS;s+=256) ps += expf(lg[(size_t)b*NS+s]-mx);
  sv[tid]=ps; __syncthreads();
  for (int st=128;st>0;st>>=1){ if (tid<st) sv[tid]+=sv[tid+st]; __syncthreads(); }
  float lse = mx + logf(sv[0]);
  for (int s=tid;s<NS;s+=256) out[((size_t)b*NT + t)*NS + s] = lg[(size_t)b*NS+s]-lse;
  if (tid==0) prevIdx[b]=ri[0];
}

// =============================== host ===============================
extern "C" void kernel_launch(void* const* d_in, const int* in_sizes, int n_in,
                              void* d_out, int out_size, void* d_ws, size_t ws_size,
                              hipStream_t stream){
  const float* mod  = (const float*)d_in[1];
  const float* mask = (const float*)d_in[2];
  const float* Wih  = (const float*)d_in[3];
  const float* Whh  = (const float*)d_in[4];
  const float* bih  = (const float*)d_in[5];
  const float* bhh  = (const float*)d_in[6];
  const float* rW[2] = {(const float*)d_in[7],  (const float*)d_in[14]};
  const float* W1[2] = {(const float*)d_in[8],  (const float*)d_in[15]};
  const float* b1[2] = {(const float*)d_in[9],  (const float*)d_in[16]};
  const float* W2[2] = {(const float*)d_in[10], (const float*)d_in[17]};
  const float* b2[2] = {(const float*)d_in[11], (const float*)d_in[18]};
  const float* W3[2] = {(const float*)d_in[12], (const float*)d_in[19]};
  const float* b3[2] = {(const float*)d_in[13], (const float*)d_in[20]};
  float* out[2];
  out[0] = (float*)d_out;
  out[1] = out[0] + (size_t)NB*NT*NS;

  float* wsf = (float*)d_ws;
  size_t off = 0;
  auto carve = [&](size_t n)->size_t{ size_t o=off; off += (n + 63) & ~(size_t)63; return o; };
  float* hbuf   = wsf + carve((size_t)NB*NH);
  float* cbuf   = wsf + carve((size_t)NB*NH);
  float* prer   = wsf + carve((size_t)NB*NPH);
  int*   sprev  = (int*)(wsf + carve(128));
  int*   eprev  = sprev + 32;
  float* m2f    = wsf + carve((size_t)NBS*NH);
  float* b2p[2] = {wsf + carve(NPH), wsf + carve(NPH)};
  float* b1p[2] = {wsf + carve(NPH), wsf + carve(NPH)};
  float* rbuf   = wsf + carve((size_t)NB*NH);
  float* gsbuf  = wsf + carve((size_t)NB*NG);
  float* lgbuf  = wsf + carve((size_t)NB*NS);
  float* W1rT[2]= {wsf + carve((size_t)NH*NPH), wsf + carve((size_t)NH*NPH)};
  ushort* modExp   = (ushort*)(wsf + carve((size_t)NBS*K1/2));
  ushort* W1exp[2] = {(ushort*)(wsf + carve((size_t)NPH*K1/2)),
                      (ushort*)(wsf + carve((size_t)NPH*K1/2))};
  ushort* W2exp[2] = {(ushort*)(wsf + carve((size_t)NPH*K2/2)),
                      (ushort*)(wsf + carve((size_t)NPH*K2/2))};
  ushort* m1exp    = (ushort*)(wsf + carve((size_t)NBS*K2/2));

  // ---- init + prep (every launch; deterministic) ----
  init_kernel<<<NB, 256, 0, stream>>>(mask, hbuf, cbuf, sprev, eprev);
  conv_mod_k<<<2048, 256, 0, stream>>>(mod, modExp);
  pad_zero_k<<<256, 256, 0, stream>>>(modExp, K1, 3*NM, K1-3*NM, NBS);
  pad_zero_k<<<256, 256, 0, stream>>>(m1exp, K2, 3*NH, K2-3*NH, NBS);
  for (int net=0; net<2; net++){
    conv_w1_k<<<2048, 256, 0, stream>>>(W1[net], W1exp[net]);
    pad_zero_k<<<64, 256, 0, stream>>>(W1exp[net], K1, 3*NM, K1-3*NM, NPH);
    conv_w2_k<<<1024, 256, 0, stream>>>(W2[net], W2exp[net]);
    pad_zero_k<<<64, 256, 0, stream>>>(W2exp[net], K2, 3*NH, K2-3*NH, NPH);
    conv_w1r_k<<<1024, 256, 0, stream>>>(W1[net], W1rT[net]);
    permv_k<<<(NPH+255)/256, 256, 0, stream>>>(b2[net], b2p[net]);
    permv_k<<<(NPH+255)/256, 256, 0, stream>>>(b1[net], b1p[net]);
  }

  dim3 ggrid(NBS/128, NPH/128);
  for (int t=0; t<NT; t++){
    lstm_gates<<<dim3(NB, NG/4), 256, 0, stream>>>(mod, sprev, eprev, hbuf,
                                                   Wih, Whh, bih, bhh, gsbuf);
    lstm_update<<<NB, 256, 0, stream>>>(gsbuf, hbuf, cbuf);
    for (int net=0; net<2; net++){
      r_kernel<<<dim3(NB, NH/4), 256, 0, stream>>>(mod, sprev, eprev, hbuf, rW[net], rbuf);
      prer_kernel<<<dim3(NB, (NPH+255)/256), 256, 0, stream>>>(rbuf, W1rT[net], b1p[net], prer);
      gemm_fused<0><<<ggrid, 256, 0, stream>>>(modExp, W1exp[net], K1, prer, (void*)m1exp);
      gemm_fused<1><<<ggrid, 256, 0, stream>>>(m1exp, W2exp[net], K2, b2p[net], (void*)m2f);
      logits_main<<<dim3(NB, 2), 256, 0, stream>>>(m1exp, m2f, W3[net], b3[net], mask, lgbuf);
      logits_fin<<<NB, 256, 0, stream>>>(lgbuf, out[net], t, net==0 ? sprev : eprev);
    }
  }
}